// Round 1
// baseline (12958.270 us; speedup 1.0000x reference)
//
#include <hip/hip_runtime.h>
#include <math.h>

#define BLOCK 128

namespace {

constexpr int   NT_   = 8;
constexpr int   HID_  = 64;
constexpr int   NB_   = 12;
constexpr int   OD_   = 74;      // 2*NB*3 + 2
constexpr float TB_   = 5.0f;
constexpr float MINW_ = 0.001f;
constexpr float MINH_ = 0.001f;
constexpr float MIND_ = 0.001f;
constexpr float LOGZ_ = -2.7568155996140185f;  // -0.5*3*log(2*pi)

__device__ __forceinline__ float softplus_(float v) {
    // matches jax.nn.softplus = logaddexp(v, 0)
    return fmaxf(v, 0.0f) + log1pf(__expf(-fabsf(v)));
}

// Rational-quadratic spline for one coordinate.
// p points at this thread's params base in LDS: p[q*BLOCK] = params[q], q in [0,37)
__device__ __forceinline__ void rq_spline_(const float* p, float xr,
                                           float& y_out, float& lad_out) {
    float uw[NB_], uh[NB_], ud[NB_ + 1];
    float mw = -1e30f, mh = -1e30f;
#pragma unroll
    for (int q = 0; q < NB_; ++q) { uw[q] = p[q * BLOCK];          mw = fmaxf(mw, uw[q]); }
#pragma unroll
    for (int q = 0; q < NB_; ++q) { uh[q] = p[(NB_ + q) * BLOCK];  mh = fmaxf(mh, uh[q]); }
#pragma unroll
    for (int q = 0; q < NB_ + 1; ++q) ud[q] = p[(2 * NB_ + q) * BLOCK];

    float ew[NB_], eh[NB_];
    float sw = 0.0f, sh = 0.0f;
#pragma unroll
    for (int q = 0; q < NB_; ++q) { ew[q] = __expf(uw[q] - mw); sw += ew[q]; }
#pragma unroll
    for (int q = 0; q < NB_; ++q) { eh[q] = __expf(uh[q] - mh); sh += eh[q]; }

    const float iw = (1.0f - MINW_ * (float)NB_) / sw;
    const float ih = (1.0f - MINH_ * (float)NB_) / sh;

    float cw[NB_ + 1], ch[NB_ + 1];
    cw[0] = -TB_; ch[0] = -TB_;
    float rw = 0.0f, rh = 0.0f;
#pragma unroll
    for (int q = 0; q < NB_; ++q) {
        rw += MINW_ + ew[q] * iw;
        rh += MINH_ + eh[q] * ih;
        cw[q + 1] = 2.0f * TB_ * rw - TB_;
        ch[q + 1] = 2.0f * TB_ * rh - TB_;
    }
    cw[NB_] = TB_;   // forced exact endpoints (reference .at[...,-1].set)
    ch[NB_] = TB_;

    const float xc = fminf(fmaxf(xr, -TB_), TB_);

    // bin index: xc >= cw_s[0] (=-TB) always true; xc >= cw_s[12] (=TB+1e-6) always false.
    int bi = 0;
#pragma unroll
    for (int q = 1; q <= NB_ - 1; ++q) bi += (xc >= cw[q]) ? 1 : 0;

    // gather knot data for bin bi via unrolled selects (no dynamic reg indexing)
    float in_cw = cw[0], cwn = cw[1], in_ch = ch[0], chn = ch[1];
    float udm1 = 0.0f, ud0 = ud[0];
#pragma unroll
    for (int q = 1; q < NB_; ++q) {
        const bool s = (bi == q);
        in_cw = s ? cw[q]     : in_cw;
        cwn   = s ? cw[q + 1] : cwn;
        in_ch = s ? ch[q]     : in_ch;
        chn   = s ? ch[q + 1] : chn;
        udm1  = s ? ud[q - 1] : udm1;
        ud0   = s ? ud[q]     : ud0;
    }
    const float in_w = cwn - in_cw;
    const float in_h = chn - in_ch;
    // padded derivative array: d[0]=d[14]=MIND+softplus(DCONST)=1 exactly
    const float d_k  = (bi == 0) ? 1.0f : (MIND_ + softplus_(udm1));
    const float d_k1 = MIND_ + softplus_(ud0);

    const float delta = in_h / in_w;
    const float theta = (xc - in_cw) / in_w;
    const float omt   = 1.0f - theta;
    const float t1m   = theta * omt;
    const float num   = in_h * (delta * theta * theta + d_k * t1m);
    const float den   = delta + (d_k + d_k1 - 2.0f * delta) * t1m;
    const float y     = in_ch + num / den;
    const float dnum  = delta * delta * (d_k1 * theta * theta + 2.0f * delta * t1m + d_k * omt * omt);
    const float lad   = __logf(dnum) - 2.0f * __logf(den);

    const bool inside = (xr >= -TB_) && (xr <= TB_);
    y_out   = inside ? y   : xr;
    lad_out = inside ? lad : 0.0f;
}

// dense layer: out[o] = bias[o] + sum_k r[k]*W[o][k], written to LDS slab (slot o)
template <int NOUT>
__device__ __forceinline__ void dense_(const float (&r)[HID_],
                                       const float* __restrict__ W,
                                       const float* __restrict__ b,
                                       float* tb, int tid) {
#pragma unroll 2
    for (int o = 0; o < NOUT; ++o) {
        const float* w = W + o * HID_;   // wave-uniform -> s_load path
        float a0 = 0.0f, a1 = 0.0f, a2 = 0.0f, a3 = 0.0f;
#pragma unroll
        for (int k = 0; k < HID_; k += 4) {
            a0 = fmaf(r[k + 0], w[k + 0], a0);
            a1 = fmaf(r[k + 1], w[k + 1], a1);
            a2 = fmaf(r[k + 2], w[k + 2], a2);
            a3 = fmaf(r[k + 3], w[k + 3], a3);
        }
        tb[o * BLOCK + tid] = (a0 + a1) + (a2 + a3) + b[o];
    }
}

__global__ __launch_bounds__(BLOCK) void nsf_kernel(
    const float* __restrict__ x,
    const float* __restrict__ W_in,  const float* __restrict__ b_in,
    const float* __restrict__ W_blk, const float* __restrict__ b_blk,
    const float* __restrict__ W_out, const float* __restrict__ b_out,
    float* __restrict__ out, int n)
{
    __shared__ float tbuf[80 * BLOCK];   // per-thread scratch slab, [slot][tid]

    const int tid = threadIdx.x;
    const int idx = blockIdx.x * BLOCK + tid;
    if (idx >= n) return;

    float z0 = x[3 * idx + 0];
    float z1 = x[3 * idx + 1];
    float z2 = x[3 * idx + 2];
    float lad_total = 0.0f;

    float h[HID_];

#pragma unroll 1
    for (int i = 0; i < NT_; ++i) {
        // z[:, ::-1]: ident = old z2, tr = (old z1, old z0)
        const float ident = z2;
        const float tr0   = z1;
        const float tr1   = z0;

        const float* Wi = W_in + i * HID_;
        const float* bi = b_in + i * HID_;
#pragma unroll
        for (int o = 0; o < HID_; ++o) h[o] = fmaf(ident, Wi[o], bi[o]);

#pragma unroll 1
        for (int j = 0; j < 2; ++j) {
            const float* WA = W_blk + (size_t)(i * 4 + 2 * j) * HID_ * HID_;
            const float* bA = b_blk + (i * 4 + 2 * j) * HID_;
            const float* WB = WA + HID_ * HID_;
            const float* bB = bA + HID_;

            float r[HID_];
#pragma unroll
            for (int k = 0; k < HID_; ++k) r[k] = fmaxf(h[k], 0.0f);

            dense_<HID_>(r, WA, bA, tbuf, tid);       // t = relu(h) @ WA^T + bA -> LDS

#pragma unroll
            for (int k = 0; k < HID_; ++k) r[k] = fmaxf(tbuf[k * BLOCK + tid], 0.0f);

            dense_<HID_>(r, WB, bB, tbuf, tid);       // t2 = relu(t) @ WB^T + bB -> LDS

#pragma unroll
            for (int k = 0; k < HID_; ++k) h[k] += tbuf[k * BLOCK + tid];   // residual
        }

        // params = h @ W_out^T + b_out  (NO relu on h here)
        dense_<OD_>(h, W_out + (size_t)i * OD_ * HID_, b_out + i * OD_, tbuf, tid);

        float y0, l0, y1, l1;
        rq_spline_(&tbuf[0 * 37 * BLOCK + tid], tr0, y0, l0);
        rq_spline_(&tbuf[1 * 37 * BLOCK + tid], tr1, y1, l1);
        lad_total += l0 + l1;

        z0 = ident;
        z1 = y0;
        z2 = y1;
    }

    out[idx] = -0.5f * (z0 * z0 + z1 * z1 + z2 * z2) + LOGZ_ + lad_total;
}

}  // namespace

extern "C" void kernel_launch(void* const* d_in, const int* in_sizes, int n_in,
                              void* d_out, int out_size, void* d_ws, size_t ws_size,
                              hipStream_t stream) {
    const float* x     = (const float*)d_in[0];
    const float* W_in  = (const float*)d_in[1];
    const float* b_in  = (const float*)d_in[2];
    const float* W_blk = (const float*)d_in[3];
    const float* b_blk = (const float*)d_in[4];
    const float* W_out = (const float*)d_in[5];
    const float* b_out = (const float*)d_in[6];
    float* out = (float*)d_out;

    const int n = in_sizes[0] / 3;
    const int grid = (n + BLOCK - 1) / BLOCK;
    nsf_kernel<<<grid, BLOCK, 0, stream>>>(x, W_in, b_in, W_blk, b_blk,
                                           W_out, b_out, out, n);
}

// Round 2
// 8890.062 us; speedup vs baseline: 1.4576x; 1.4576x over previous
//
#include <hip/hip_runtime.h>
#include <math.h>

#define BLOCK 64

namespace {

constexpr int   NT_   = 8;
constexpr int   HID_  = 64;
constexpr int   NB_   = 12;
constexpr int   OD_   = 74;      // 2*NB*3 + 2
constexpr float TB_   = 5.0f;
constexpr float MINW_ = 0.001f;
constexpr float MINH_ = 0.001f;
constexpr float MIND_ = 0.001f;
constexpr float LOGZ_ = -2.7568155996140185f;  // -0.5*3*log(2*pi)

// LDS slot map (per-thread column, 64 slots x BLOCK threads):
//   GEMM phases:   slots 0..63  = staging for layer outputs
//   spline phase:  slots 0..36  = params (uw 0..11, uh 12..23, ud 24..36)
//                  slots 37..49 = cw[0..12]   (KW = 37)
//                  slots 50..62 = ch[0..12]   (KH = 50)
constexpr int KW_ = 37;
constexpr int KH_ = 50;

__device__ __forceinline__ float softplus_(float v) {
    return fmaxf(v, 0.0f) + log1pf(__expf(-fabsf(v)));
}

// Rational-quadratic spline; Tb = &T_sh[tid], params at Tb[q*BLOCK].
__device__ __forceinline__ void rq_spline_(float* Tb, float xr,
                                           float& y_out, float& lad_out) {
    float mw = -1e30f, mh = -1e30f;
#pragma unroll
    for (int q = 0; q < NB_; ++q) mw = fmaxf(mw, Tb[q * BLOCK]);
#pragma unroll
    for (int q = 0; q < NB_; ++q) mh = fmaxf(mh, Tb[(NB_ + q) * BLOCK]);

    float ew[NB_], eh[NB_];
    float sw = 0.0f, sh = 0.0f;
#pragma unroll
    for (int q = 0; q < NB_; ++q) { ew[q] = __expf(Tb[q * BLOCK] - mw);          sw += ew[q]; }
#pragma unroll
    for (int q = 0; q < NB_; ++q) { eh[q] = __expf(Tb[(NB_ + q) * BLOCK] - mh);  sh += eh[q]; }

    const float iw = (1.0f - MINW_ * (float)NB_) / sw;
    const float ih = (1.0f - MINH_ * (float)NB_) / sh;

    const float xc = fminf(fmaxf(xr, -TB_), TB_);

    // build knot arrays in LDS, count bin on the fly
    Tb[KW_ * BLOCK] = -TB_;
    Tb[KH_ * BLOCK] = -TB_;
    float rw = 0.0f, rh = 0.0f;
    int bi = 0;
#pragma unroll
    for (int q = 0; q < NB_; ++q) {
        rw += MINW_ + ew[q] * iw;
        rh += MINH_ + eh[q] * ih;
        const float cwv = (q == NB_ - 1) ? TB_ : fmaf(2.0f * TB_, rw, -TB_);
        const float chv = (q == NB_ - 1) ? TB_ : fmaf(2.0f * TB_, rh, -TB_);
        Tb[(KW_ + 1 + q) * BLOCK] = cwv;
        Tb[(KH_ + 1 + q) * BLOCK] = chv;
        if (q < NB_ - 1) bi += (xc >= cwv) ? 1 : 0;
    }

    // dynamic-index gathers (bank = tid%32 regardless of bi -> 2-way, free)
    const float in_cw = Tb[(KW_ + bi) * BLOCK];
    const float cwn   = Tb[(KW_ + 1 + bi) * BLOCK];
    const float in_ch = Tb[(KH_ + bi) * BLOCK];
    const float chn   = Tb[(KH_ + 1 + bi) * BLOCK];
    // padded derivs: d[0]=1 exactly; d_k = d[bi], d_k1 = d[bi+1]
    const float d_k  = (bi == 0) ? 1.0f : (MIND_ + softplus_(Tb[(23 + bi) * BLOCK]));
    const float d_k1 = MIND_ + softplus_(Tb[(24 + bi) * BLOCK]);

    const float in_w  = cwn - in_cw;
    const float in_h  = chn - in_ch;
    const float delta = in_h / in_w;
    const float theta = (xc - in_cw) / in_w;
    const float omt   = 1.0f - theta;
    const float t1m   = theta * omt;
    const float num   = in_h * (delta * theta * theta + d_k * t1m);
    const float den   = delta + (d_k + d_k1 - 2.0f * delta) * t1m;
    const float y     = in_ch + num / den;
    const float dnum  = delta * delta * (d_k1 * theta * theta + 2.0f * delta * t1m + d_k * omt * omt);
    const float lad   = __logf(dnum) - 2.0f * __logf(den);

    const bool inside = (xr >= -TB_) && (xr <= TB_);
    y_out   = inside ? y   : xr;
    lad_out = inside ? lad : 0.0f;
}

// out[o] = b[o] + sum_k in[k]*W[o][k]  -> Tb[o*BLOCK], optional fused relu
template <int NOUT, bool RELU>
__device__ __forceinline__ void dense_(const float (&in)[HID_],
                                       const float* __restrict__ W,
                                       const float* __restrict__ b,
                                       float* Tb) {
#pragma unroll 2
    for (int o = 0; o < NOUT; ++o) {
        const float* w = W + o * HID_;   // wave-uniform -> scalar-load path
        float a0 = 0.0f, a1 = 0.0f, a2 = 0.0f, a3 = 0.0f;
#pragma unroll
        for (int k = 0; k < HID_; k += 4) {
            a0 = fmaf(in[k + 0], w[k + 0], a0);
            a1 = fmaf(in[k + 1], w[k + 1], a1);
            a2 = fmaf(in[k + 2], w[k + 2], a2);
            a3 = fmaf(in[k + 3], w[k + 3], a3);
        }
        const float v = (a0 + a1) + (a2 + a3) + b[o];
        Tb[o * BLOCK] = RELU ? fmaxf(v, 0.0f) : v;
    }
}

__global__ __launch_bounds__(BLOCK, 2) void nsf_kernel(
    const float* __restrict__ x,
    const float* __restrict__ W_in,  const float* __restrict__ b_in,
    const float* __restrict__ W_blk, const float* __restrict__ b_blk,
    const float* __restrict__ W_out, const float* __restrict__ b_out,
    float* __restrict__ out, int n)
{
    __shared__ float T_sh[64 * BLOCK];   // 16 KB: per-thread 64-slot column

    const int tid = threadIdx.x;
    const int idx = blockIdx.x * BLOCK + tid;
    if (idx >= n) return;

    float* Tb = &T_sh[tid];

    float z0 = x[3 * idx + 0];
    float z1 = x[3 * idx + 1];
    float z2 = x[3 * idx + 2];
    float lad_total = 0.0f;

    float h[HID_];
    float r[HID_];

#pragma unroll 1
    for (int i = 0; i < NT_; ++i) {
        // z[:, ::-1]: ident = old z2, tr = (old z1, old z0)
        const float ident = z2;
        const float tr0   = z1;
        const float tr1   = z0;

        const float* Wi = W_in + i * HID_;
        const float* bi = b_in + i * HID_;
#pragma unroll
        for (int o = 0; o < HID_; ++o) h[o] = fmaf(ident, Wi[o], bi[o]);

#pragma unroll 1
        for (int j = 0; j < 2; ++j) {
            const float* WA = W_blk + (size_t)(i * 4 + 2 * j) * HID_ * HID_;
            const float* bA = b_blk + (i * 4 + 2 * j) * HID_;
            const float* WB = WA + HID_ * HID_;
            const float* bB = bA + HID_;

#pragma unroll
            for (int k = 0; k < HID_; ++k) r[k] = fmaxf(h[k], 0.0f);

            dense_<HID_, true>(r, WA, bA, Tb);     // relu(t1) -> slots 0..63

#pragma unroll
            for (int k = 0; k < HID_; ++k) r[k] = Tb[k * BLOCK];

            dense_<HID_, false>(r, WB, bB, Tb);    // t2 -> slots 0..63

#pragma unroll
            for (int k = 0; k < HID_; ++k) h[k] += Tb[k * BLOCK];   // residual
        }

        // out head in two 37-wide halves; spline consumes each half in place
        const float* Wo = W_out + (size_t)i * OD_ * HID_;
        const float* bo = b_out + i * OD_;

        float y0, l0, y1, l1;
        dense_<37, false>(h, Wo, bo, Tb);                     // params[0..37)
        rq_spline_(Tb, tr0, y0, l0);
        dense_<37, false>(h, Wo + 37 * HID_, bo + 37, Tb);    // params[37..74)
        rq_spline_(Tb, tr1, y1, l1);

        lad_total += l0 + l1;

        z0 = ident;
        z1 = y0;
        z2 = y1;
    }

    out[idx] = -0.5f * (z0 * z0 + z1 * z1 + z2 * z2) + LOGZ_ + lad_total;
}

}  // namespace

extern "C" void kernel_launch(void* const* d_in, const int* in_sizes, int n_in,
                              void* d_out, int out_size, void* d_ws, size_t ws_size,
                              hipStream_t stream) {
    const float* x     = (const float*)d_in[0];
    const float* W_in  = (const float*)d_in[1];
    const float* b_in  = (const float*)d_in[2];
    const float* W_blk = (const float*)d_in[3];
    const float* b_blk = (const float*)d_in[4];
    const float* W_out = (const float*)d_in[5];
    const float* b_out = (const float*)d_in[6];
    float* out = (float*)d_out;

    const int n = in_sizes[0] / 3;
    const int grid = (n + BLOCK - 1) / BLOCK;
    nsf_kernel<<<grid, BLOCK, 0, stream>>>(x, W_in, b_in, W_blk, b_blk,
                                           W_out, b_out, out, n);
}